// Round 1
// 617.279 us; speedup vs baseline: 1.3958x; 1.3958x over previous
//
#include <hip/hip_runtime.h>
#include <stdint.h>

#define RDIM 14
#define CDIM 64
#define NFRAMES 4

// 4 waves/block. Each block stages a 256-row X tile into LDS with async DMA;
// each wave then computes 64 consecutive rows with lane = output column.
constexpr int BLOCK = 256;
constexpr int TILE_ROWS = 256;
constexpr int ROWS_PER_WAVE = 64;
constexpr int X_TILE_BYTES = TILE_ROWS * RDIM * 4;    // 14336 B
constexpr int CHUNK_BYTES  = 64 * 16;                 // one global_load_lds dwordx4 issue
constexpr int N_CHUNKS     = X_TILE_BYTES / CHUNK_BYTES;  // 14

typedef const __attribute__((address_space(1))) uint32_t* gptr_t;
typedef __attribute__((address_space(3))) uint32_t* lptr_t;

__global__ __launch_bounds__(BLOCK, 4) void frame_proj_kernel(
    const float* __restrict__ X,      // (batch, 14)
    const int* __restrict__ ids,      // (batch,)
    const float* __restrict__ W,      // (4, 64, 14)
    const float* __restrict__ B,      // (4, 64)
    float* __restrict__ out,          // (batch, 64)
    int batch)
{
    __shared__ float xs_lds[TILE_ROWS * RDIM];   // 14336 B, packed 56 B rows

    const int tid  = threadIdx.x;
    const int lane = tid & 63;
    const int wid  = __builtin_amdgcn_readfirstlane(tid >> 6);

    const int tileBase = blockIdx.x * TILE_ROWS;
    const int tileRows = min(TILE_ROWS, batch - tileBase);

    // ---- ids for this wave's 64 rows: one coalesced 256B load into a VGPR ----
    const int waveRow0 = wid * ROWS_PER_WAVE;        // within tile
    const int gRow0    = tileBase + waveRow0;        // global row base
    int idv = 0;
    if (gRow0 + lane < batch) idv = ids[gRow0 + lane];

    // ---- stage X tile into LDS (linear layout == DMA lane order) ----
    if (tileRows == TILE_ROWS) {
        const char* gsrc = (const char*)(X + (size_t)tileBase * RDIM);
        for (int c = wid; c < N_CHUNKS; c += 4) {
            __builtin_amdgcn_global_load_lds(
                (gptr_t)(const void*)(gsrc + c * CHUNK_BYTES + lane * 16),
                (lptr_t)(void*)((char*)xs_lds + c * CHUNK_BYTES),
                16, 0, 0);
        }
    } else {
        for (int i = tid; i < tileRows * RDIM; i += BLOCK)
            xs_lds[i] = X[(size_t)tileBase * RDIM + i];
    }

    // ---- per-lane weight cache (lane = column), PINNED into VGPRs ----
    float w[NFRAMES][RDIM];
    float bb[NFRAMES];
#pragma unroll
    for (int e = 0; e < NFRAMES; ++e) {
#pragma unroll
        for (int k = 0; k < RDIM; ++k)
            w[e][k] = W[(e * CDIM + lane) * RDIM + k];
        bb[e] = B[e * CDIM + lane];
    }
    // Empty asm forces the 60 floats to be materialized and kept in VGPRs;
    // without this the compiler re-fetches weights inside the row loop
    // (prev kernel: VGPR_Count=32 -> cache never existed in registers).
#pragma unroll
    for (int e = 0; e < NFRAMES; ++e) {
#pragma unroll
        for (int k = 0; k < RDIM; ++k)
            asm volatile("" : "+v"(w[e][k]));
        asm volatile("" : "+v"(bb[e]));
    }

    __syncthreads();   // drains the LDS-DMA (vmcnt) + barrier

    const int nrows = min(ROWS_PER_WAVE, tileRows - waveRow0);
    const float2* xr = (const float2*)xs_lds + waveRow0 * (RDIM / 2);
    float* orow = out + (size_t)gRow0 * CDIM + lane;

    for (int r = 0; r < nrows; ++r) {
        // Expert id: in-register, no memory on the critical path.
        const int id = __builtin_amdgcn_readlane(idv, r);

        // x row: 7x ds_read_b64, uniform address -> broadcast, conflict-free.
        float xv[RDIM];
#pragma unroll
        for (int k = 0; k < RDIM / 2; ++k) {
            float2 v = xr[r * (RDIM / 2) + k];
            xv[2 * k]     = v.x;
            xv[2 * k + 1] = v.y;
        }

        auto dot = [&](const float (&wk)[RDIM], float bias) {
            float a0 = bias, a1 = 0.0f;   // two chains: halve dependent-FMA latency
#pragma unroll
            for (int k = 0; k < RDIM; k += 2) {
                a0 = fmaf(xv[k],     wk[k],     a0);
                a1 = fmaf(xv[k + 1], wk[k + 1], a1);
            }
            return a0 + a1;
        };

        float acc;
        if (id == 0)      acc = dot(w[0], bb[0]);   // wave-uniform scalar branch
        else if (id == 1) acc = dot(w[1], bb[1]);
        else if (id == 2) acc = dot(w[2], bb[2]);
        else              acc = dot(w[3], bb[3]);

        // 64 lanes x 4B = 256B coalesced store per row.
        orow[(size_t)r * CDIM] = acc;
    }
}

extern "C" void kernel_launch(void* const* d_in, const int* in_sizes, int n_in,
                              void* d_out, int out_size, void* d_ws, size_t ws_size,
                              hipStream_t stream) {
    const float* X   = (const float*)d_in[0];
    const int*   ids = (const int*)d_in[1];
    const float* W   = (const float*)d_in[2];
    const float* B   = (const float*)d_in[3];
    float* out = (float*)d_out;

    const int batch = in_sizes[1];  // frame_type_ids element count

    const int grid = (batch + TILE_ROWS - 1) / TILE_ROWS;
    frame_proj_kernel<<<grid, BLOCK, 0, stream>>>(X, ids, W, B, out, batch);
}